// Round 11
// baseline (120.985 us; speedup 1.0000x reference)
//
#include <hip/hip_runtime.h>

// PointPillarScatter: scatter sparse pillar features into a dense BEV grid.
// Grid: NX=432, NY=496, NZ=1, C=64, B=8, P=96000 pillars (5.6% occupancy).
// Out 0: [B, C, NY, NX] f32 ; Out 1: [B, 1, NY, NX] f32, concatenated flat.
//
// Round-11: r10 (1 float4/thread linear sweep + nt stores + u16 map,
// 101.4us) + occupancy BITMAP front-end. 1 bit/cell (214 KB): empty
// 4-cell groups (~80% of lanes) read only their bitmap word (shared by
// 8 lanes -> L1 broadcast); only occupied groups touch the u16 map.
// Read-side L2 traffic: 223 MB -> ~60 MB. Bits are authoritative, so the
// 3.4 MB map memset is dropped (unoccupied map entries never read).

namespace {

constexpr int kNX = 432;
constexpr int kNY = 496;
constexpr int kS  = kNX * kNY;   // 214272 spatial cells per sample
constexpr int kS4 = kS / 4;      // 53568 float4s per plane
constexpr int kWB = kS / 32;     // 6696 bitmap words per batch (exact)
constexpr int kC  = 64;
constexpr int kB  = 8;

typedef float f32x4 __attribute__((ext_vector_type(4)));
typedef unsigned short u16;
typedef u16 u16x4 __attribute__((ext_vector_type(4)));

__global__ void scatter_idx_kernel(const int* __restrict__ coords,
                                   u16* __restrict__ map,
                                   unsigned* __restrict__ bmap,
                                   int P, int PB, int BS) {
  int p = blockIdx.x * blockDim.x + threadIdx.x;
  if (p >= P) return;
  // coords row p = (b, z, y, x) as int32
  int4 c = reinterpret_cast<const int4*>(coords)[p];
  long flat = (long)c.x * kS + (long)c.y + (long)c.z * kNX + (long)c.w;
  if (flat >= 0 && flat < (long)BS) {
    int fi = (int)flat;
    map[fi] = (u16)(p - c.x * PB);
    atomicOr(&bmap[fi >> 5], 1u << (fi & 31));
  }
}

// One thread = one output float4, swept linearly over the whole 446 MB.
// plane 0..511   -> out0 (b = plane>>6, c = plane&63)
// plane 512..519 -> out1 (b = plane-512)
__global__ __launch_bounds__(256) void gather_fill_kernel(
    const u16* __restrict__ map,       // [B*S] per-batch pillar idx (valid where bit set)
    const unsigned* __restrict__ bmap, // [B*S/32] occupancy bits
    const float* __restrict__ pf,      // [P, 64]
    const float* __restrict__ vnp,     // [P]
    float* __restrict__ out,
    int total4, int PB) {
  int g = blockIdx.x * blockDim.x + threadIdx.x;
  if (g >= total4) return;
  int plane = g / kS4;               // const-div -> mul_hi
  int j = g - plane * kS4;           // float4 index within plane

  f32x4 v = (f32x4)(0.f);
  if (plane < kB * kC) {
    int b = plane >> 6;
    int c = plane & 63;
    unsigned bw  = bmap[b * kWB + (j >> 3)];
    unsigned nib = (bw >> ((j & 7) << 2)) & 0xFu;
    if (nib) {
      u16x4 m = reinterpret_cast<const u16x4*>(map)[b * kS4 + j];
      int pb = b * PB;
      if (nib & 1u) v.x = pf[(pb + m.x) * kC + c];
      if (nib & 2u) v.y = pf[(pb + m.y) * kC + c];
      if (nib & 4u) v.z = pf[(pb + m.z) * kC + c];
      if (nib & 8u) v.w = pf[(pb + m.w) * kC + c];
    }
  } else {
    int b = plane - kB * kC;
    unsigned bw  = bmap[b * kWB + (j >> 3)];
    unsigned nib = (bw >> ((j & 7) << 2)) & 0xFu;
    if (nib) {
      u16x4 m = reinterpret_cast<const u16x4*>(map)[b * kS4 + j];
      int pb = b * PB;
      if (nib & 1u) v.x = vnp[pb + m.x];
      if (nib & 2u) v.y = vnp[pb + m.y];
      if (nib & 4u) v.z = vnp[pb + m.z];
      if (nib & 8u) v.w = vnp[pb + m.w];
    }
  }
  // streaming store: evict-first / no L2 allocate; output is never re-read
  __builtin_nontemporal_store(v, reinterpret_cast<f32x4*>(out) + g);
}

// ---- fallback if ws_size is too small: memset + direct scatter
__global__ void direct_scatter_kernel(const int* __restrict__ coords,
                                      const float* __restrict__ pf,
                                      const float* __restrict__ vnp,
                                      float* __restrict__ out,
                                      int P, int B) {
  int p = blockIdx.x;          // one wave per pillar
  int c = threadIdx.x;         // 64 channels
  if (p >= P) return;
  int4 cc = reinterpret_cast<const int4*>(coords)[p];
  int b = cc.x;
  int s = cc.y + cc.z * kNX + cc.w;
  out[(b * kC + c) * kS + s] = pf[p * kC + c];
  if (c == 0) out[B * kC * kS + b * kS + s] = vnp[p];
}

}  // namespace

extern "C" void kernel_launch(void* const* d_in, const int* in_sizes, int n_in,
                              void* d_out, int out_size, void* d_ws, size_t ws_size,
                              hipStream_t stream) {
  const float* pf     = (const float*)d_in[0];  // [P,64] f32
  const int*   coords = (const int*)d_in[1];    // [P,4] int32 (b,z,y,x)
  const float* vnp    = (const float*)d_in[2];  // [P] f32
  const int B = kB;                              // fixed by problem config
  const int P = in_sizes[0] / kC;
  const int PB = P / B;                          // 12000 pillars per batch
  const int BS = B * kS;                         // 1,714,176
  float* out = (float*)d_out;

  const size_t map_bytes  = (size_t)BS * sizeof(u16);     // 3,428,352
  const size_t bmap_bytes = (size_t)(BS / 8);             //   214,272
  if (ws_size >= map_bytes + bmap_bytes && PB <= 0xFFFF) {
    u16* map = (u16*)d_ws;
    unsigned* bmap = (unsigned*)((char*)d_ws + map_bytes);
    // No map memset needed: bitmap bits gate every map read.
    (void)hipMemsetAsync(bmap, 0x00, bmap_bytes, stream);
    scatter_idx_kernel<<<(P + 255) / 256, 256, 0, stream>>>(
        coords, map, bmap, P, PB, BS);
    const int total4 = (B * kC * kS + B * kS) / 4;  // 27,855,360 float4s
    gather_fill_kernel<<<(total4 + 255) / 256, 256, 0, stream>>>(
        map, bmap, pf, vnp, out, total4, PB);
  } else {
    (void)hipMemsetAsync(out, 0, (size_t)out_size * sizeof(float), stream);
    direct_scatter_kernel<<<P, 64, 0, stream>>>(coords, pf, vnp, out, P, B);
  }
}

// Round 12
// 83.859 us; speedup vs baseline: 1.4427x; 1.4427x over previous
//
#include <hip/hip_runtime.h>

// PointPillarScatter: scatter sparse pillar features into a dense BEV grid.
// Grid: NX=432, NY=496, NZ=1, C=64, B=8, P=96000 pillars (5.6% occupancy).
// Out 0: [B, C, NY, NX] f32 ; Out 1: [B, 1, NY, NX] f32, concatenated flat.
//
// Round-12: EXACT r10 (1 float4/thread linear sweep + nt stores + u16 map,
// 101.4us; r11's bitmap gating regressed via dependent-load chain) + ONE
// variable: bijective chunked XCD swizzle on the fill grid. Each XCD owns a
// contiguous 1/8 of the sweep (~one batch's planes), so its map slice
// (429KB) + pf slice (3MB) stay L2-resident across its 64 channel passes
// instead of all 8 XCDs streaming the same batch's data over the fabric.

namespace {

constexpr int kNX = 432;
constexpr int kNY = 496;
constexpr int kS  = kNX * kNY;   // 214272 spatial cells per sample
constexpr int kS4 = kS / 4;      // 53568 float4s per plane
constexpr int kC  = 64;
constexpr int kB  = 8;
constexpr int kNXCD = 8;

typedef float f32x4 __attribute__((ext_vector_type(4)));
typedef unsigned short u16;
typedef u16 u16x4 __attribute__((ext_vector_type(4)));

__global__ void scatter_idx_kernel(const int* __restrict__ coords,
                                   u16* __restrict__ map,
                                   int P, int PB, int BS) {
  int p = blockIdx.x * blockDim.x + threadIdx.x;
  if (p >= P) return;
  // coords row p = (b, z, y, x) as int32
  int4 c = reinterpret_cast<const int4*>(coords)[p];
  long flat = (long)c.x * kS + (long)c.y + (long)c.z * kNX + (long)c.w;
  if (flat >= 0 && flat < (long)BS) map[(int)flat] = (u16)(p - c.x * PB);
}

// One thread = one output float4; block ids remapped so each XCD sweeps a
// CONTIGUOUS chunk of the output (bijective m204 chunking, nwg % 8 != 0 ok).
// plane 0..511   -> out0 (b = plane>>6, c = plane&63)
// plane 512..519 -> out1 (b = plane-512)
__global__ __launch_bounds__(256) void gather_fill_kernel(
    const u16* __restrict__ map,     // [B*S] per-batch pillar idx or 0xFFFF
    const float* __restrict__ pf,    // [P, 64]
    const float* __restrict__ vnp,   // [P]
    float* __restrict__ out,
    int total4, int PB) {
  // bijective chunked XCD swizzle: q = nwg/8, r = nwg%8
  int nwg = gridDim.x;
  int q = nwg >> 3;                  // 13601 for nwg=108810
  int r = nwg & 7;                   // 2
  int xcd = blockIdx.x & 7;
  int pos = blockIdx.x >> 3;
  int nb = (xcd < r) ? (xcd * (q + 1) + pos)
                     : (r * (q + 1) + (xcd - r) * q + pos);
  int g = nb * 256 + (int)threadIdx.x;
  if (g >= total4) return;
  int plane = g / kS4;               // const-div -> mul_hi
  int j = g - plane * kS4;           // float4 index within plane

  f32x4 v = (f32x4)(0.f);
  if (plane < kB * kC) {
    int b = plane >> 6;
    int c = plane & 63;
    u16x4 m = reinterpret_cast<const u16x4*>(map)[b * kS4 + j];
    if ((m.x & m.y & m.z & m.w) != 0xFFFF) {   // any occupied
      int pb = b * PB;
      if (m.x != 0xFFFF) v.x = pf[(pb + m.x) * kC + c];
      if (m.y != 0xFFFF) v.y = pf[(pb + m.y) * kC + c];
      if (m.z != 0xFFFF) v.z = pf[(pb + m.z) * kC + c];
      if (m.w != 0xFFFF) v.w = pf[(pb + m.w) * kC + c];
    }
  } else {
    int b = plane - kB * kC;
    u16x4 m = reinterpret_cast<const u16x4*>(map)[b * kS4 + j];
    int pb = b * PB;
    if (m.x != 0xFFFF) v.x = vnp[pb + m.x];
    if (m.y != 0xFFFF) v.y = vnp[pb + m.y];
    if (m.z != 0xFFFF) v.z = vnp[pb + m.z];
    if (m.w != 0xFFFF) v.w = vnp[pb + m.w];
  }
  // streaming store: evict-first / no L2 allocate; output is never re-read
  __builtin_nontemporal_store(v, reinterpret_cast<f32x4*>(out) + g);
}

// ---- fallback if ws_size is too small for the map: memset + direct scatter
__global__ void direct_scatter_kernel(const int* __restrict__ coords,
                                      const float* __restrict__ pf,
                                      const float* __restrict__ vnp,
                                      float* __restrict__ out,
                                      int P, int B) {
  int p = blockIdx.x;          // one wave per pillar
  int c = threadIdx.x;         // 64 channels
  if (p >= P) return;
  int4 cc = reinterpret_cast<const int4*>(coords)[p];
  int b = cc.x;
  int s = cc.y + cc.z * kNX + cc.w;
  out[(b * kC + c) * kS + s] = pf[p * kC + c];
  if (c == 0) out[B * kC * kS + b * kS + s] = vnp[p];
}

}  // namespace

extern "C" void kernel_launch(void* const* d_in, const int* in_sizes, int n_in,
                              void* d_out, int out_size, void* d_ws, size_t ws_size,
                              hipStream_t stream) {
  const float* pf     = (const float*)d_in[0];  // [P,64] f32
  const int*   coords = (const int*)d_in[1];    // [P,4] int32 (b,z,y,x)
  const float* vnp    = (const float*)d_in[2];  // [P] f32
  const int B = kB;                              // fixed by problem config
  const int P = in_sizes[0] / kC;
  const int PB = P / B;                          // 12000 pillars per batch
  const int BS = B * kS;                         // 1,714,176
  float* out = (float*)d_out;

  const size_t map_bytes = (size_t)BS * sizeof(u16);
  if (ws_size >= map_bytes && PB <= 0xFFFF) {
    u16* map = (u16*)d_ws;
    (void)hipMemsetAsync(map, 0xFF, map_bytes, stream);  // all 0xFFFF = empty
    scatter_idx_kernel<<<(P + 255) / 256, 256, 0, stream>>>(coords, map, P, PB, BS);
    const int total4 = (B * kC * kS + B * kS) / 4;  // 27,855,360 float4s
    gather_fill_kernel<<<(total4 + 255) / 256, 256, 0, stream>>>(
        map, pf, vnp, out, total4, PB);
  } else {
    (void)hipMemsetAsync(out, 0, (size_t)out_size * sizeof(float), stream);
    direct_scatter_kernel<<<P, 64, 0, stream>>>(coords, pf, vnp, out, P, B);
  }
}

// Round 13
// 83.120 us; speedup vs baseline: 1.4555x; 1.0089x over previous
//
#include <hip/hip_runtime.h>

// PointPillarScatter: scatter sparse pillar features into a dense BEV grid.
// Grid: NX=432, NY=496, NZ=1, C=64, B=8, P=96000 pillars (5.6% occupancy).
// Out 0: [B, C, NY, NX] f32 ; Out 1: [B, 1, NY, NX] f32, concatenated flat.
//
// Round-13: EXACT r12 (linear sweep + nt stores + u16 map + bijective
// chunked XCD swizzle, 83.9us) with ONE variable: block size 256 -> 1024.
// 4x fewer blocks (108810 -> 27203) = fewer scheduling quanta; each block
// is a 16KB contiguous store burst.

namespace {

constexpr int kNX = 432;
constexpr int kNY = 496;
constexpr int kS  = kNX * kNY;   // 214272 spatial cells per sample
constexpr int kS4 = kS / 4;      // 53568 float4s per plane
constexpr int kC  = 64;
constexpr int kB  = 8;

typedef float f32x4 __attribute__((ext_vector_type(4)));
typedef unsigned short u16;
typedef u16 u16x4 __attribute__((ext_vector_type(4)));

__global__ void scatter_idx_kernel(const int* __restrict__ coords,
                                   u16* __restrict__ map,
                                   int P, int PB, int BS) {
  int p = blockIdx.x * blockDim.x + threadIdx.x;
  if (p >= P) return;
  // coords row p = (b, z, y, x) as int32
  int4 c = reinterpret_cast<const int4*>(coords)[p];
  long flat = (long)c.x * kS + (long)c.y + (long)c.z * kNX + (long)c.w;
  if (flat >= 0 && flat < (long)BS) map[(int)flat] = (u16)(p - c.x * PB);
}

// One thread = one output float4; block ids remapped so each XCD sweeps a
// CONTIGUOUS chunk of the output (bijective m204 chunking, any nwg).
// plane 0..511   -> out0 (b = plane>>6, c = plane&63)
// plane 512..519 -> out1 (b = plane-512)
__global__ __launch_bounds__(1024) void gather_fill_kernel(
    const u16* __restrict__ map,     // [B*S] per-batch pillar idx or 0xFFFF
    const float* __restrict__ pf,    // [P, 64]
    const float* __restrict__ vnp,   // [P]
    float* __restrict__ out,
    int total4, int PB) {
  // bijective chunked XCD swizzle: q = nwg/8, r = nwg%8
  int nwg = gridDim.x;
  int q = nwg >> 3;
  int r = nwg & 7;
  int xcd = blockIdx.x & 7;
  int pos = blockIdx.x >> 3;
  int nb = (xcd < r) ? (xcd * (q + 1) + pos)
                     : (r * (q + 1) + (xcd - r) * q + pos);
  int g = nb * 1024 + (int)threadIdx.x;
  if (g >= total4) return;
  int plane = g / kS4;               // const-div -> mul_hi
  int j = g - plane * kS4;           // float4 index within plane

  f32x4 v = (f32x4)(0.f);
  if (plane < kB * kC) {
    int b = plane >> 6;
    int c = plane & 63;
    u16x4 m = reinterpret_cast<const u16x4*>(map)[b * kS4 + j];
    if ((m.x & m.y & m.z & m.w) != 0xFFFF) {   // any occupied
      int pb = b * PB;
      if (m.x != 0xFFFF) v.x = pf[(pb + m.x) * kC + c];
      if (m.y != 0xFFFF) v.y = pf[(pb + m.y) * kC + c];
      if (m.z != 0xFFFF) v.z = pf[(pb + m.z) * kC + c];
      if (m.w != 0xFFFF) v.w = pf[(pb + m.w) * kC + c];
    }
  } else {
    int b = plane - kB * kC;
    u16x4 m = reinterpret_cast<const u16x4*>(map)[b * kS4 + j];
    int pb = b * PB;
    if (m.x != 0xFFFF) v.x = vnp[pb + m.x];
    if (m.y != 0xFFFF) v.y = vnp[pb + m.y];
    if (m.z != 0xFFFF) v.z = vnp[pb + m.z];
    if (m.w != 0xFFFF) v.w = vnp[pb + m.w];
  }
  // streaming store: evict-first / no L2 allocate; output is never re-read
  __builtin_nontemporal_store(v, reinterpret_cast<f32x4*>(out) + g);
}

// ---- fallback if ws_size is too small for the map: memset + direct scatter
__global__ void direct_scatter_kernel(const int* __restrict__ coords,
                                      const float* __restrict__ pf,
                                      const float* __restrict__ vnp,
                                      float* __restrict__ out,
                                      int P, int B) {
  int p = blockIdx.x;          // one wave per pillar
  int c = threadIdx.x;         // 64 channels
  if (p >= P) return;
  int4 cc = reinterpret_cast<const int4*>(coords)[p];
  int b = cc.x;
  int s = cc.y + cc.z * kNX + cc.w;
  out[(b * kC + c) * kS + s] = pf[p * kC + c];
  if (c == 0) out[B * kC * kS + b * kS + s] = vnp[p];
}

}  // namespace

extern "C" void kernel_launch(void* const* d_in, const int* in_sizes, int n_in,
                              void* d_out, int out_size, void* d_ws, size_t ws_size,
                              hipStream_t stream) {
  const float* pf     = (const float*)d_in[0];  // [P,64] f32
  const int*   coords = (const int*)d_in[1];    // [P,4] int32 (b,z,y,x)
  const float* vnp    = (const float*)d_in[2];  // [P] f32
  const int B = kB;                              // fixed by problem config
  const int P = in_sizes[0] / kC;
  const int PB = P / B;                          // 12000 pillars per batch
  const int BS = B * kS;                         // 1,714,176
  float* out = (float*)d_out;

  const size_t map_bytes = (size_t)BS * sizeof(u16);
  if (ws_size >= map_bytes && PB <= 0xFFFF) {
    u16* map = (u16*)d_ws;
    (void)hipMemsetAsync(map, 0xFF, map_bytes, stream);  // all 0xFFFF = empty
    scatter_idx_kernel<<<(P + 255) / 256, 256, 0, stream>>>(coords, map, P, PB, BS);
    const int total4 = (B * kC * kS + B * kS) / 4;   // 27,855,360 float4s
    const int nwg = (total4 + 1023) / 1024;          // 27,203
    gather_fill_kernel<<<nwg, 1024, 0, stream>>>(
        map, pf, vnp, out, total4, PB);
  } else {
    (void)hipMemsetAsync(out, 0, (size_t)out_size * sizeof(float), stream);
    direct_scatter_kernel<<<P, 64, 0, stream>>>(coords, pf, vnp, out, P, B);
  }
}